// Round 2
// baseline (1271.955 us; speedup 1.0000x reference)
//
#include <hip/hip_runtime.h>
#include <math.h>

#define TOK 4096      // B*S
#define DM 2048
#define SL 2048
#define NHEAD 16
#define DKH 128
#define DFF 8192

typedef float f32x4 __attribute__((ext_vector_type(4)));
typedef __bf16 bf16x8 __attribute__((ext_vector_type(8)));

__device__ __forceinline__ unsigned short f2bf(float f) {
  unsigned int u = __float_as_uint(f);
  u += 0x7fffu + ((u >> 16) & 1u);
  return (unsigned short)(u >> 16);
}

__device__ __forceinline__ void gload_lds16(const void* g, void* l) {
  __builtin_amdgcn_global_load_lds(
      (const __attribute__((address_space(1))) unsigned int*)g,
      (__attribute__((address_space(3))) unsigned int*)l, 16, 0, 0);
}

// ---------------- fused dual layernorm (shared mean/var), fp32 -> bf16 x2 ----
__global__ __launch_bounds__(256) void ln_cast_kernel(
    const float* __restrict__ x, const float* __restrict__ g1,
    const float* __restrict__ be1, const float* __restrict__ g2,
    const float* __restrict__ be2, unsigned short* __restrict__ attn_in,
    unsigned short* __restrict__ ff_in) {
  __shared__ float redS[4], redQ[4];
  long row = blockIdx.x;
  int t = threadIdx.x;
  const float4* xr = (const float4*)(x + row * DM);
  float4 a = xr[t];
  float4 b = xr[t + 256];
  float s = a.x + a.y + a.z + a.w + b.x + b.y + b.z + b.w;
  float q = a.x * a.x + a.y * a.y + a.z * a.z + a.w * a.w +
            b.x * b.x + b.y * b.y + b.z * b.z + b.w * b.w;
  for (int o = 32; o > 0; o >>= 1) {
    s += __shfl_xor(s, o, 64);
    q += __shfl_xor(q, o, 64);
  }
  int wave = t >> 6;
  if ((t & 63) == 0) { redS[wave] = s; redQ[wave] = q; }
  __syncthreads();
  s = redS[0] + redS[1] + redS[2] + redS[3];
  q = redQ[0] + redQ[1] + redQ[2] + redQ[3];
  float mean = s * (1.0f / DM);
  float var = q * (1.0f / DM) - mean * mean;
  float rs = rsqrtf(var + 1e-5f);
  float vals[8] = {a.x, a.y, a.z, a.w, b.x, b.y, b.z, b.w};
  long base = row * DM;
#pragma unroll
  for (int i = 0; i < 8; ++i) {
    int c = (i < 4) ? (4 * t + i) : (1024 + 4 * t + (i - 4));
    float nv = (vals[i] - mean) * rs;
    attn_in[base + c] = f2bf(nv * g1[c] + be1[c]);
    ff_in[base + c] = f2bf(nv * g2[c] + be2[c]);
  }
}

// ---------------- fp32 [R,C] -> bf16 [C,R] ----------------------------------
__global__ __launch_bounds__(256) void transpose_cast(
    const float* __restrict__ in, unsigned short* __restrict__ out, int R, int C) {
  __shared__ float tile[32][33];
  int bx = blockIdx.x << 5;  // col tile of in
  int by = blockIdx.y << 5;  // row tile of in
  int tx = threadIdx.x & 31, ty = threadIdx.x >> 5;
#pragma unroll
  for (int i = ty; i < 32; i += 8) tile[i][tx] = in[(long)(by + i) * C + bx + tx];
  __syncthreads();
#pragma unroll
  for (int i = ty; i < 32; i += 8)
    out[(long)(bx + i) * R + by + tx] = f2bf(tile[tx][i]);
}

// ---------------- V slice of qkv (bf16) -> v_t[bh][dk][s] --------------------
__global__ __launch_bounds__(256) void transpose_v(
    const unsigned short* __restrict__ qkv, unsigned short* __restrict__ v_t) {
  __shared__ unsigned short tile[32][33];
  int z = blockIdx.z;
  int b = z >> 4, h = z & 15;
  int sx = blockIdx.x << 5;  // s tile
  int dx = blockIdx.y << 5;  // dk tile
  int tx = threadIdx.x & 31, ty = threadIdx.x >> 5;
  const unsigned short* src = qkv + (long)b * SL * (3 * DM) + 2 * DM + h * DKH;
#pragma unroll
  for (int i = ty; i < 32; i += 8)
    tile[i][tx] = src[(long)(sx + i) * (3 * DM) + dx + tx];
  __syncthreads();
  unsigned short* dst = v_t + (long)z * DKH * SL;
#pragma unroll
  for (int i = ty; i < 32; i += 8)
    dst[(long)(dx + i) * SL + sx + tx] = tile[tx][i];
}

// ---------------- in-place row softmax, fp32 -> bf16 -------------------------
__global__ __launch_bounds__(256) void softmax_kernel(float* __restrict__ scores) {
  __shared__ float red[4];
  long row = blockIdx.x;
  float* rp = scores + row * (long)SL;
  int t = threadIdx.x;
  int wave = t >> 6;
  float4 a = ((const float4*)rp)[t];
  float4 b = ((const float4*)rp)[t + 256];
  const float sc = 0.08838834764831845f;  // 1/sqrt(128)
  float v[8] = {a.x, a.y, a.z, a.w, b.x, b.y, b.z, b.w};
  float mx = -1e30f;
#pragma unroll
  for (int i = 0; i < 8; ++i) { v[i] *= sc; mx = fmaxf(mx, v[i]); }
  for (int o = 32; o > 0; o >>= 1) mx = fmaxf(mx, __shfl_xor(mx, o, 64));
  if ((t & 63) == 0) red[wave] = mx;
  __syncthreads();
  mx = fmaxf(fmaxf(red[0], red[1]), fmaxf(red[2], red[3]));
  __syncthreads();
  float sum = 0.f;
#pragma unroll
  for (int i = 0; i < 8; ++i) { v[i] = __expf(v[i] - mx); sum += v[i]; }
  for (int o = 32; o > 0; o >>= 1) sum += __shfl_xor(sum, o, 64);
  if ((t & 63) == 0) red[wave] = sum;
  __syncthreads();
  float inv = 1.0f / (red[0] + red[1] + red[2] + red[3]);
  unsigned short* op = (unsigned short*)rp;  // all global reads done (barrier above)
#pragma unroll
  for (int i = 0; i < 4; ++i) op[4 * t + i] = f2bf(v[i] * inv);
#pragma unroll
  for (int i = 0; i < 4; ++i) op[1024 + 4 * t + i] = f2bf(v[4 + i] * inv);
}

// ---------------- generic C = A * B^T bf16 MFMA GEMM -------------------------
// A: [M,K] bf16 (lda), B: [N,K] bf16 (ldb), 128x128 tile, BK=32.
// EPI: 0=bf16 store, 1=f32 store, 2=bias+gelu->bf16, 3=x+acc->f32,
//      4=out += lscale*(acc+bias)
struct GemmP {
  const unsigned short* A;
  const unsigned short* B;
  const float* bias;
  const float* xadd;
  const float* lscale;
  float* outf;
  unsigned short* outb;
  int K;
  int lda, ldb, ldc;
  long sAz, sAo, sAi;
  long sBz, sBo, sBi;
  long sCz, sCo, sCi;
  int innerN, zbase;
};

template <int EPI>
__global__ __launch_bounds__(256, 2) void gemm_bt(GemmP p) {
  __shared__ __align__(16) unsigned short As[128 * 32];
  __shared__ __align__(16) unsigned short Bs[128 * 32];
  const int tid = threadIdx.x;
  const int wave = tid >> 6;
  const int lane = tid & 63;
  const int quad = lane >> 4;
  const int l16 = lane & 15;
  const int wm = (wave >> 1) << 6;
  const int wn = (wave & 1) << 6;
  const long m0 = (long)blockIdx.y << 7;
  const long n0 = (long)blockIdx.x << 7;
  const int zz = p.zbase + blockIdx.z;
  const int zq = zz / p.innerN;
  const int zr = zz - zq * p.innerN;
  const unsigned short* Ab =
      p.A + (long)blockIdx.z * p.sAz + (long)zq * p.sAo + (long)zr * p.sAi;
  const unsigned short* Bb =
      p.B + (long)blockIdx.z * p.sBz + (long)zq * p.sBo + (long)zr * p.sBi;
  const long offC = (long)blockIdx.z * p.sCz + (long)zq * p.sCo + (long)zr * p.sCi;

  f32x4 acc[4][4];
#pragma unroll
  for (int i = 0; i < 4; ++i)
#pragma unroll
    for (int j = 0; j < 4; ++j)
#pragma unroll
      for (int r = 0; r < 4; ++r) acc[i][j][r] = 0.0f;

  // staging geometry: flat f in [0,512), 16B per f; row = f>>2, col8 = (f&3)*8
  const int r0 = tid >> 2, c0 = (tid & 3) << 3;
  const int f1 = 256 + tid;
  const int r1 = f1 >> 2, c1 = (f1 & 3) << 3;
  unsigned short* lA0 = As + (long)(tid & ~63) * 8;          // wave-uniform base
  unsigned short* lA1 = As + (long)(256 + (tid & ~63)) * 8;
  unsigned short* lB0 = Bs + (long)(tid & ~63) * 8;
  unsigned short* lB1 = Bs + (long)(256 + (tid & ~63)) * 8;

  for (int k0 = 0; k0 < p.K; k0 += 32) {
    gload_lds16(Ab + (m0 + r0) * (long)p.lda + k0 + c0, lA0);
    gload_lds16(Ab + (m0 + r1) * (long)p.lda + k0 + c1, lA1);
    gload_lds16(Bb + (n0 + r0) * (long)p.ldb + k0 + c0, lB0);
    gload_lds16(Bb + (n0 + r1) * (long)p.ldb + k0 + c1, lB1);
    __syncthreads();  // compiler emits vmcnt(0) drain before barrier
    bf16x8 af[4], bf[4];
#pragma unroll
    for (int i = 0; i < 4; ++i)
      af[i] = *(const bf16x8*)(As + ((wm + i * 16 + l16) << 5) + (quad << 3));
#pragma unroll
    for (int i = 0; i < 4; ++i)
      bf[i] = *(const bf16x8*)(Bs + ((wn + i * 16 + l16) << 5) + (quad << 3));
#pragma unroll
    for (int i = 0; i < 4; ++i)
#pragma unroll
      for (int j = 0; j < 4; ++j)
        acc[i][j] =
            __builtin_amdgcn_mfma_f32_16x16x32_bf16(af[i], bf[j], acc[i][j], 0, 0, 0);
    __syncthreads();
  }

#pragma unroll
  for (int i = 0; i < 4; ++i)
#pragma unroll
    for (int j = 0; j < 4; ++j)
#pragma unroll
      for (int r = 0; r < 4; ++r) {
        long m = m0 + wm + i * 16 + quad * 4 + r;
        long n = n0 + wn + j * 16 + l16;
        long idx = offC + m * (long)p.ldc + n;
        float v = acc[i][j][r];
        if (EPI == 0) {
          p.outb[idx] = f2bf(v);
        } else if (EPI == 1) {
          p.outf[idx] = v;
        } else if (EPI == 2) {
          float u = v + p.bias[n];
          p.outb[idx] = f2bf(0.5f * u * (1.0f + erff(u * 0.70710678118654752f)));
        } else if (EPI == 3) {
          p.outf[idx] = p.xadd[m * (long)p.ldc + n] + v;
        } else {
          p.outf[idx] += p.lscale[n] * (v + p.bias[n]);
        }
      }
}

// ----------------------------------------------------------------------------
// Workspace layout (liveness-overlaid; fixed part = 128 MiB):
//   [0,48)    Q    : qkv bf16               (live: QKV gemm .. end of attention)
//   [48,64)   Ctx  : ctx bf16               (live: attention loop .. W_O gemm)
//   [0,64)    H    : h1 bf16  = Q + Ctx     (live: FF1 .. FF2; Q/Ctx dead by then)
//   [64,80)   A    : attn_in bf16, then v_t (attn_in dead after QKV gemm)
//   [80,96)   F    : ff_in bf16             (live until FF1)
//   [96,128)  W    : current weight bf16    (transposed just-in-time, one at a time)
//   [128,..)  S    : scores chunk (chunk*16 MiB) — or overlaid on W if ws is tight
//                    (W is idle during the attention loop; w_o transposed after it)
extern "C" void kernel_launch(void* const* d_in, const int* in_sizes, int n_in,
                              void* d_out, int out_size, void* d_ws, size_t ws_size,
                              hipStream_t stream) {
  const float* x = (const float*)d_in[0];
  const float* w_qkv = (const float*)d_in[2];
  const float* w_o = (const float*)d_in[3];
  const float* g1 = (const float*)d_in[4];
  const float* be1 = (const float*)d_in[5];
  const float* g2 = (const float*)d_in[6];
  const float* be2 = (const float*)d_in[7];
  const float* w1 = (const float*)d_in[8];
  const float* b1 = (const float*)d_in[9];
  const float* w2 = (const float*)d_in[10];
  const float* b2 = (const float*)d_in[11];
  const float* ls = (const float*)d_in[12];
  float* out = (float*)d_out;

  unsigned char* ws = (unsigned char*)d_ws;
  const size_t MiB = 1024 * 1024;
  unsigned short* qkv = (unsigned short*)(ws);                 // 48 MiB
  unsigned short* ctx = (unsigned short*)(ws + 48 * MiB);      // 16 MiB
  unsigned short* h1 = (unsigned short*)(ws);                  // 64 MiB (=Q+Ctx)
  unsigned short* attn_in = (unsigned short*)(ws + 64 * MiB);  // 16 MiB
  unsigned short* v_t = (unsigned short*)(ws + 64 * MiB);      // 16 MiB (after QKV)
  unsigned short* ff_in = (unsigned short*)(ws + 80 * MiB);    // 16 MiB
  unsigned short* wbuf = (unsigned short*)(ws + 96 * MiB);     // 32 MiB

  int chunk;
  float* scores;
  if (ws_size >= 640 * MiB)      { chunk = 32; scores = (float*)(ws + 128 * MiB); }
  else if (ws_size >= 384 * MiB) { chunk = 16; scores = (float*)(ws + 128 * MiB); }
  else if (ws_size >= 256 * MiB) { chunk = 8;  scores = (float*)(ws + 128 * MiB); }
  else if (ws_size >= 192 * MiB) { chunk = 4;  scores = (float*)(ws + 128 * MiB); }
  else if (ws_size >= 160 * MiB) { chunk = 2;  scores = (float*)(ws + 128 * MiB); }
  else if (ws_size >= 128 * MiB) { chunk = 2;  scores = (float*)(ws + 96 * MiB); }
  else                           { chunk = 1;  scores = (float*)(ws + 96 * MiB); }

  dim3 blk(256);

  ln_cast_kernel<<<TOK, blk, 0, stream>>>(x, g1, be1, g2, be2, attn_in, ff_in);

  {  // qkv = attn_in @ w_qkv  (bf16 out)
    transpose_cast<<<dim3(3 * DM / 32, DM / 32), blk, 0, stream>>>(w_qkv, wbuf, DM, 3 * DM);
    GemmP p = {};
    p.A = attn_in; p.B = wbuf; p.outb = qkv;
    p.K = DM; p.lda = DM; p.ldb = DM; p.ldc = 3 * DM; p.innerN = 1;
    gemm_bt<0><<<dim3(3 * DM / 128, TOK / 128, 1), blk, 0, stream>>>(p);
  }

  transpose_v<<<dim3(SL / 32, DKH / 32, 32), blk, 0, stream>>>(qkv, v_t);

  for (int c0 = 0; c0 < 32; c0 += chunk) {
    {  // scores[z] = q(bh) @ k(bh)^T  (f32)
      GemmP p = {};
      p.A = qkv; p.B = qkv + DM; p.outf = scores;
      p.K = DKH; p.lda = 3 * DM; p.ldb = 3 * DM; p.ldc = SL;
      p.sAo = (long)SL * 3 * DM; p.sAi = DKH;
      p.sBo = (long)SL * 3 * DM; p.sBi = DKH;
      p.sCz = (long)SL * SL;
      p.innerN = NHEAD; p.zbase = c0;
      gemm_bt<1><<<dim3(SL / 128, SL / 128, chunk), blk, 0, stream>>>(p);
    }
    softmax_kernel<<<chunk * SL, blk, 0, stream>>>(scores);
    {  // ctx(bh) = P @ V   (P bf16 in-place in scores rows, lda = 2*SL)
      GemmP p = {};
      p.A = (const unsigned short*)scores; p.B = v_t; p.outb = ctx;
      p.K = SL; p.lda = 2 * SL; p.ldb = SL; p.ldc = DM;
      p.sAz = (long)SL * 2 * SL;
      p.sBo = (long)NHEAD * DKH * SL; p.sBi = (long)DKH * SL;
      p.sCo = (long)SL * DM; p.sCi = DKH;
      p.innerN = NHEAD; p.zbase = c0;
      gemm_bt<0><<<dim3(DKH / 128, SL / 128, chunk), blk, 0, stream>>>(p);
    }
  }

  {  // out = x + ctx @ w_o
    transpose_cast<<<dim3(DM / 32, DM / 32), blk, 0, stream>>>(w_o, wbuf, DM, DM);
    GemmP p = {};
    p.A = ctx; p.B = wbuf; p.outf = out; p.xadd = x;
    p.K = DM; p.lda = DM; p.ldb = DM; p.ldc = DM; p.innerN = 1;
    gemm_bt<3><<<dim3(DM / 128, TOK / 128, 1), blk, 0, stream>>>(p);
  }
  {  // h1 = gelu(ff_in @ w1 + b1)  (bf16) — qkv & ctx dead, h1 overlays them
    transpose_cast<<<dim3(DFF / 32, DM / 32), blk, 0, stream>>>(w1, wbuf, DM, DFF);
    GemmP p = {};
    p.A = ff_in; p.B = wbuf; p.outb = h1; p.bias = b1;
    p.K = DM; p.lda = DM; p.ldb = DM; p.ldc = DFF; p.innerN = 1;
    gemm_bt<2><<<dim3(DFF / 128, TOK / 128, 1), blk, 0, stream>>>(p);
  }
  {  // out += layer_scale * (h1 @ w2 + b2)
    transpose_cast<<<dim3(DM / 32, DFF / 32), blk, 0, stream>>>(w2, wbuf, DFF, DM);
    GemmP p = {};
    p.A = h1; p.B = wbuf; p.outf = out; p.bias = b2; p.lscale = ls;
    p.K = DFF; p.lda = DFF; p.ldb = DFF; p.ldc = DM; p.innerN = 1;
    gemm_bt<4><<<dim3(DM / 128, TOK / 128, 1), blk, 0, stream>>>(p);
  }
}